// Round 1
// baseline (64.724 us; speedup 1.0000x reference)
//
#include <hip/hip_runtime.h>

#define N_NODES 50000
#define N_EDGES 800000
#define FEAT    128

// ws layout: acc[N_NODES] floats, then sum[1] float.

__global__ void zero_ws(float* __restrict__ p, int n) {
    int i = blockIdx.x * blockDim.x + threadIdx.x;
    if (i < n) p[i] = 0.0f;
}

__global__ void edge_scatter(const float* __restrict__ li,
                             const float* __restrict__ w,
                             const int* __restrict__ row,
                             const int* __restrict__ col,
                             float* __restrict__ acc, int E) {
    int e = blockIdx.x * blockDim.x + threadIdx.x;
    if (e < E) {
        // only feature column 0 matters for the final scalar
        float v = w[e] * li[(long)col[e] * FEAT];
        atomicAdd(&acc[row[e]], v);
    }
}

__global__ void relu_sum(const float* __restrict__ acc, int n,
                         float* __restrict__ sum) {
    float local = 0.0f;
    for (int i = blockIdx.x * blockDim.x + threadIdx.x; i < n;
         i += gridDim.x * blockDim.x) {
        local += fmaxf(acc[i], 0.0f);
    }
    // wave-64 shuffle reduce
    #pragma unroll
    for (int off = 32; off > 0; off >>= 1)
        local += __shfl_down(local, off, 64);
    __shared__ float s[4];  // 256 threads = 4 waves
    int wid = threadIdx.x >> 6;
    if ((threadIdx.x & 63) == 0) s[wid] = local;
    __syncthreads();
    if (threadIdx.x == 0) {
        float t = s[0] + s[1] + s[2] + s[3];
        atomicAdd(sum, t);
    }
}

__global__ void finalize(const float* __restrict__ sum,
                         float* __restrict__ out) {
    out[0] = 1.0f / (1.0f + expf(-sum[0]));
}

extern "C" void kernel_launch(void* const* d_in, const int* in_sizes, int n_in,
                              void* d_out, int out_size, void* d_ws, size_t ws_size,
                              hipStream_t stream) {
    const float* li  = (const float*)d_in[0];   // [N_NODES, FEAT]
    const float* w   = (const float*)d_in[1];   // [N_EDGES]
    const int*   row = (const int*)d_in[2];     // [N_EDGES]
    const int*   col = (const int*)d_in[3];     // [N_EDGES]
    float* out = (float*)d_out;

    float* acc = (float*)d_ws;          // N_NODES floats
    float* sum = acc + N_NODES;         // 1 float

    int nz = N_NODES + 1;
    zero_ws<<<(nz + 255) / 256, 256, 0, stream>>>(acc, nz);

    edge_scatter<<<(N_EDGES + 255) / 256, 256, 0, stream>>>(li, w, row, col, acc, N_EDGES);

    relu_sum<<<256, 256, 0, stream>>>(acc, N_NODES, sum);

    finalize<<<1, 1, 0, stream>>>(sum, out);
}

// Round 3
// 61.040 us; speedup vs baseline: 1.0604x; 1.0604x over previous
//
#include <hip/hip_runtime.h>

#define N_NODES 50000
#define N_EDGES 800000
#define FEAT    128

// ws layout: acc[N_NODES] f32 | li0[N_NODES] f32 | sum f32 | ticket u32

__global__ void pack_zero(const float* __restrict__ li,
                          float* __restrict__ li0,
                          float* __restrict__ acc,
                          float* __restrict__ sum,
                          unsigned* __restrict__ ticket) {
    int i = blockIdx.x * blockDim.x + threadIdx.x;
    if (i < N_NODES) {
        li0[i] = li[(long)i * FEAT];   // strided gather of column 0
        acc[i] = 0.0f;
    }
    if (i == N_NODES) {
        *sum = 0.0f;
        *ticket = 0u;
    }
}

__global__ void edge_scatter4(const float* __restrict__ li0,
                              const float* __restrict__ w,
                              const int* __restrict__ row,
                              const int* __restrict__ col,
                              float* __restrict__ acc) {
    int t = blockIdx.x * blockDim.x + threadIdx.x;
    const int Q = N_EDGES / 4;  // 200000
    if (t < Q) {
        float4 wv = ((const float4*)w)[t];
        int4   rv = ((const int4*)row)[t];
        int4   cv = ((const int4*)col)[t];
        // 4 independent L2-resident gathers in flight
        float g0 = li0[cv.x];
        float g1 = li0[cv.y];
        float g2 = li0[cv.z];
        float g3 = li0[cv.w];
        atomicAdd(&acc[rv.x], wv.x * g0);
        atomicAdd(&acc[rv.y], wv.y * g1);
        atomicAdd(&acc[rv.z], wv.z * g2);
        atomicAdd(&acc[rv.w], wv.w * g3);
    }
}

__global__ void relu_sum_fin(const float* __restrict__ acc,
                             float* __restrict__ sum,
                             unsigned* __restrict__ ticket,
                             float* __restrict__ out) {
    const int Q = N_NODES / 4;  // 12500
    float local = 0.0f;
    for (int i = blockIdx.x * blockDim.x + threadIdx.x; i < Q;
         i += gridDim.x * blockDim.x) {
        float4 a = ((const float4*)acc)[i];
        local += fmaxf(a.x, 0.0f) + fmaxf(a.y, 0.0f) +
                 fmaxf(a.z, 0.0f) + fmaxf(a.w, 0.0f);
    }
    #pragma unroll
    for (int off = 32; off > 0; off >>= 1)
        local += __shfl_down(local, off, 64);
    __shared__ float s[4];
    int wid = threadIdx.x >> 6;
    if ((threadIdx.x & 63) == 0) s[wid] = local;
    __syncthreads();
    if (threadIdx.x == 0) {
        atomicAdd(sum, s[0] + s[1] + s[2] + s[3]);
        __threadfence();
        unsigned old = atomicAdd(ticket, 1u);
        if (old == gridDim.x - 1) {       // last block to finish
            __threadfence();
            float v = *(volatile float*)sum;
            out[0] = 1.0f / (1.0f + expf(-v));
        }
    }
}

extern "C" void kernel_launch(void* const* d_in, const int* in_sizes, int n_in,
                              void* d_out, int out_size, void* d_ws, size_t ws_size,
                              hipStream_t stream) {
    const float* li  = (const float*)d_in[0];
    const float* w   = (const float*)d_in[1];
    const int*   row = (const int*)d_in[2];
    const int*   col = (const int*)d_in[3];
    float* out = (float*)d_out;

    float*    acc    = (float*)d_ws;
    float*    li0    = acc + N_NODES;
    float*    sum    = li0 + N_NODES;
    unsigned* ticket = (unsigned*)(sum + 1);

    pack_zero<<<(N_NODES + 256) / 256, 256, 0, stream>>>(li, li0, acc, sum, ticket);

    edge_scatter4<<<(N_EDGES / 4 + 255) / 256, 256, 0, stream>>>(li0, w, row, col, acc);

    relu_sum_fin<<<49, 256, 0, stream>>>(acc, sum, ticket, out);
}

// Round 4
// 57.383 us; speedup vs baseline: 1.1279x; 1.0637x over previous
//
#include <hip/hip_runtime.h>

#define N_NODES 50000
#define N_EDGES 800000
#define FEAT    128
#define K_REP   16

// ws layout: acc[K_REP][N_NODES] f32 | li0[N_NODES] f32 | sum f32 | ticket u32

__global__ void pack_zero(const float* __restrict__ li,
                          float* __restrict__ li0,
                          float* __restrict__ acc,
                          float* __restrict__ sum,
                          unsigned* __restrict__ ticket) {
    int i = blockIdx.x * blockDim.x + threadIdx.x;
    if (i < K_REP * N_NODES) acc[i] = 0.0f;
    if (i < N_NODES) li0[i] = li[(long)i * FEAT];  // pack feature column 0
    if (i == K_REP * N_NODES) {
        *sum = 0.0f;
        *ticket = 0u;
    }
}

__global__ void edge_scatter4(const float* __restrict__ li0,
                              const float* __restrict__ w,
                              const int* __restrict__ row,
                              const int* __restrict__ col,
                              float* __restrict__ acc) {
    int t = blockIdx.x * blockDim.x + threadIdx.x;
    const int Q = N_EDGES / 4;  // 200000
    if (t < Q) {
        float4 wv = ((const float4*)w)[t];
        int4   rv = ((const int4*)row)[t];
        int4   cv = ((const int4*)col)[t];
        float g0 = li0[cv.x];
        float g1 = li0[cv.y];
        float g2 = li0[cv.z];
        float g3 = li0[cv.w];
        // replica pick decorrelates contention; cuts per-line atomic chains ~16x
        float* base = acc + (size_t)((threadIdx.x ^ blockIdx.x) & (K_REP - 1)) * N_NODES;
        atomicAdd(&base[rv.x], wv.x * g0);
        atomicAdd(&base[rv.y], wv.y * g1);
        atomicAdd(&base[rv.z], wv.z * g2);
        atomicAdd(&base[rv.w], wv.w * g3);
    }
}

__global__ void relu_sum_fin(const float* __restrict__ acc,
                             float* __restrict__ sum,
                             unsigned* __restrict__ ticket,
                             float* __restrict__ out) {
    const int Q = N_NODES / 4;  // 12500 float4 groups
    float local = 0.0f;
    for (int i = blockIdx.x * blockDim.x + threadIdx.x; i < Q;
         i += gridDim.x * blockDim.x) {
        float ax = 0.0f, ay = 0.0f, az = 0.0f, aw = 0.0f;
        #pragma unroll
        for (int k = 0; k < K_REP; ++k) {
            float4 a = ((const float4*)(acc + (size_t)k * N_NODES))[i];
            ax += a.x; ay += a.y; az += a.z; aw += a.w;
        }
        local += fmaxf(ax, 0.0f) + fmaxf(ay, 0.0f) +
                 fmaxf(az, 0.0f) + fmaxf(aw, 0.0f);
    }
    #pragma unroll
    for (int off = 32; off > 0; off >>= 1)
        local += __shfl_down(local, off, 64);
    __shared__ float s[4];
    int wid = threadIdx.x >> 6;
    if ((threadIdx.x & 63) == 0) s[wid] = local;
    __syncthreads();
    if (threadIdx.x == 0) {
        atomicAdd(sum, s[0] + s[1] + s[2] + s[3]);
        __threadfence();
        unsigned old = atomicAdd(ticket, 1u);
        if (old == gridDim.x - 1) {  // last block finalizes
            __threadfence();
            float v = *(volatile float*)sum;
            out[0] = 1.0f / (1.0f + expf(-v));
        }
    }
}

extern "C" void kernel_launch(void* const* d_in, const int* in_sizes, int n_in,
                              void* d_out, int out_size, void* d_ws, size_t ws_size,
                              hipStream_t stream) {
    const float* li  = (const float*)d_in[0];
    const float* w   = (const float*)d_in[1];
    const int*   row = (const int*)d_in[2];
    const int*   col = (const int*)d_in[3];
    float* out = (float*)d_out;

    float*    acc    = (float*)d_ws;                 // K_REP * N_NODES
    float*    li0    = acc + (size_t)K_REP * N_NODES;
    float*    sum    = li0 + N_NODES;
    unsigned* ticket = (unsigned*)(sum + 1);

    int nz = K_REP * N_NODES + 1;
    pack_zero<<<(nz + 255) / 256, 256, 0, stream>>>(li, li0, acc, sum, ticket);

    edge_scatter4<<<(N_EDGES / 4 + 255) / 256, 256, 0, stream>>>(li0, w, row, col, acc);

    relu_sum_fin<<<49, 256, 0, stream>>>(acc, sum, ticket, out);
}

// Round 5
// 37.917 us; speedup vs baseline: 1.7070x; 1.5134x over previous
//
#include <hip/hip_runtime.h>

#define N_NODES 50000
#define N_EDGES 800000
#define FEAT    128

#define NRANGE  4
#define RBLKS   64                     // edge slices (blocks per range)
#define RNODES  (N_NODES / NRANGE)     // 12500 nodes per range -> 50 KB LDS
#define SLICE_E (N_EDGES / RBLKS)      // 12500 edges per slice
#define SLICE_Q (SLICE_E / 4)          // 3125 float4/int4 quads per slice

// primary ws layout: li0[N_NODES] | partial[NRANGE*RBLKS][RNODES] | sum | ticket
// fallback ws layout: acc[N_NODES] | li0[N_NODES] | sum | ticket

__global__ void pack_zero(const float* __restrict__ li,
                          float* __restrict__ li0,
                          float* __restrict__ sum,
                          unsigned* __restrict__ ticket) {
    int i = blockIdx.x * blockDim.x + threadIdx.x;
    if (i < N_NODES) li0[i] = li[(long)i * FEAT];   // pack feature column 0
    if (i == 0) { *sum = 0.0f; *ticket = 0u; }
}

// ---------------- primary path: LDS-accumulated range filter ----------------

__global__ __launch_bounds__(256) void range_accum(
        const float* __restrict__ li0,
        const float* __restrict__ w,
        const int* __restrict__ row,
        const int* __restrict__ col,
        float* __restrict__ partial) {
    __shared__ float accl[RNODES];                  // 50 KB
    const int r  = blockIdx.x & (NRANGE - 1);       // node range
    const int s  = blockIdx.x >> 2;                 // edge slice
    const int lo = r * RNODES;

    for (int i = threadIdx.x; i < RNODES; i += 256) accl[i] = 0.0f;
    __syncthreads();

    const float4* wq = (const float4*)w   + (size_t)s * SLICE_Q;
    const int4*   rq = (const int4*)row   + (size_t)s * SLICE_Q;
    const int4*   cq = (const int4*)col   + (size_t)s * SLICE_Q;

    for (int q = threadIdx.x; q < SLICE_Q; q += 256) {
        float4 wv = wq[q];
        int4   rv = rq[q];
        int4   cv = cq[q];
        int a;
        a = rv.x - lo; if ((unsigned)a < RNODES) atomicAdd(&accl[a], wv.x * li0[cv.x]);
        a = rv.y - lo; if ((unsigned)a < RNODES) atomicAdd(&accl[a], wv.y * li0[cv.y]);
        a = rv.z - lo; if ((unsigned)a < RNODES) atomicAdd(&accl[a], wv.z * li0[cv.z]);
        a = rv.w - lo; if ((unsigned)a < RNODES) atomicAdd(&accl[a], wv.w * li0[cv.w]);
    }
    __syncthreads();

    float4* pdst = (float4*)(partial + (size_t)blockIdx.x * RNODES);
    const float4* psrc = (const float4*)accl;
    for (int i = threadIdx.x; i < RNODES / 4; i += 256) pdst[i] = psrc[i];
}

__global__ void reduce_fin(const float* __restrict__ partial,
                           float* __restrict__ sum,
                           unsigned* __restrict__ ticket,
                           float* __restrict__ out) {
    int n = blockIdx.x * blockDim.x + threadIdx.x;
    float local = 0.0f;
    if (n < N_NODES) {
        int r  = n / RNODES;
        int nl = n - r * RNODES;
        const float* base = partial + ((size_t)r * RBLKS) * RNODES + nl;
        float acc = 0.0f;
        #pragma unroll 8
        for (int b = 0; b < RBLKS; ++b) acc += base[(size_t)b * RNODES];
        local = fmaxf(acc, 0.0f);
    }
    #pragma unroll
    for (int off = 32; off > 0; off >>= 1)
        local += __shfl_down(local, off, 64);
    __shared__ float sm[4];
    int wid = threadIdx.x >> 6;
    if ((threadIdx.x & 63) == 0) sm[wid] = local;
    __syncthreads();
    if (threadIdx.x == 0) {
        atomicAdd(sum, sm[0] + sm[1] + sm[2] + sm[3]);
        __threadfence();
        unsigned old = atomicAdd(ticket, 1u);
        if (old == gridDim.x - 1) {
            __threadfence();
            float v = *(volatile float*)sum;
            out[0] = 1.0f / (1.0f + expf(-v));
        }
    }
}

// ---------------- fallback path (ws too small): global atomics ----------------

__global__ void zero_acc(float* __restrict__ acc) {
    int i = blockIdx.x * blockDim.x + threadIdx.x;
    if (i < N_NODES) acc[i] = 0.0f;
}

__global__ void edge_scatter4(const float* __restrict__ li0,
                              const float* __restrict__ w,
                              const int* __restrict__ row,
                              const int* __restrict__ col,
                              float* __restrict__ acc) {
    int t = blockIdx.x * blockDim.x + threadIdx.x;
    if (t < N_EDGES / 4) {
        float4 wv = ((const float4*)w)[t];
        int4   rv = ((const int4*)row)[t];
        int4   cv = ((const int4*)col)[t];
        atomicAdd(&acc[rv.x], wv.x * li0[cv.x]);
        atomicAdd(&acc[rv.y], wv.y * li0[cv.y]);
        atomicAdd(&acc[rv.z], wv.z * li0[cv.z]);
        atomicAdd(&acc[rv.w], wv.w * li0[cv.w]);
    }
}

__global__ void relu_sum_fin(const float* __restrict__ acc,
                             float* __restrict__ sum,
                             unsigned* __restrict__ ticket,
                             float* __restrict__ out) {
    float local = 0.0f;
    for (int i = blockIdx.x * blockDim.x + threadIdx.x; i < N_NODES / 4;
         i += gridDim.x * blockDim.x) {
        float4 a = ((const float4*)acc)[i];
        local += fmaxf(a.x, 0.0f) + fmaxf(a.y, 0.0f) +
                 fmaxf(a.z, 0.0f) + fmaxf(a.w, 0.0f);
    }
    #pragma unroll
    for (int off = 32; off > 0; off >>= 1)
        local += __shfl_down(local, off, 64);
    __shared__ float sm[4];
    int wid = threadIdx.x >> 6;
    if ((threadIdx.x & 63) == 0) sm[wid] = local;
    __syncthreads();
    if (threadIdx.x == 0) {
        atomicAdd(sum, sm[0] + sm[1] + sm[2] + sm[3]);
        __threadfence();
        unsigned old = atomicAdd(ticket, 1u);
        if (old == gridDim.x - 1) {
            __threadfence();
            float v = *(volatile float*)sum;
            out[0] = 1.0f / (1.0f + expf(-v));
        }
    }
}

extern "C" void kernel_launch(void* const* d_in, const int* in_sizes, int n_in,
                              void* d_out, int out_size, void* d_ws, size_t ws_size,
                              hipStream_t stream) {
    const float* li  = (const float*)d_in[0];
    const float* w   = (const float*)d_in[1];
    const int*   row = (const int*)d_in[2];
    const int*   col = (const int*)d_in[3];
    float* out = (float*)d_out;

    size_t need = (size_t)N_NODES * 4                       // li0
                + (size_t)NRANGE * RBLKS * RNODES * 4       // partials (12.8 MB)
                + 16;

    if (ws_size >= need) {
        float*    li0     = (float*)d_ws;
        float*    partial = li0 + N_NODES;
        float*    sum     = partial + (size_t)NRANGE * RBLKS * RNODES;
        unsigned* ticket  = (unsigned*)(sum + 1);

        pack_zero<<<(N_NODES + 255) / 256, 256, 0, stream>>>(li, li0, sum, ticket);
        range_accum<<<NRANGE * RBLKS, 256, 0, stream>>>(li0, w, row, col, partial);
        reduce_fin<<<(N_NODES + 255) / 256, 256, 0, stream>>>(partial, sum, ticket, out);
    } else {
        float*    acc    = (float*)d_ws;
        float*    li0    = acc + N_NODES;
        float*    sum    = li0 + N_NODES;
        unsigned* ticket = (unsigned*)(sum + 1);

        pack_zero<<<(N_NODES + 255) / 256, 256, 0, stream>>>(li, li0, sum, ticket);
        zero_acc<<<(N_NODES + 255) / 256, 256, 0, stream>>>(acc);
        edge_scatter4<<<(N_EDGES / 4 + 255) / 256, 256, 0, stream>>>(li0, w, row, col, acc);
        relu_sum_fin<<<49, 256, 0, stream>>>(acc, sum, ticket, out);
    }
}

// Round 6
// 29.490 us; speedup vs baseline: 2.1948x; 1.2858x over previous
//
#include <hip/hip_runtime.h>

#define N_NODES 50000
#define N_EDGES 800000
#define FEAT    128

#define NRANGE  4
#define RBLKS   64                     // edge slices (blocks per range)
#define RNODES  (N_NODES / NRANGE)     // 12500 nodes per range -> 50 KB LDS
#define SLICE_Q (N_EDGES / RBLKS / 4)  // 3125 quads per slice
#define TB      1024                   // 16 waves/CU at 50 KB LDS (1 block/CU)

// primary ws layout: li0[N_NODES] | partial[NRANGE*RBLKS][RNODES] | sum | ticket
// fallback ws layout: acc[N_NODES] | li0[N_NODES] | sum | ticket

__global__ void pack_zero(const float* __restrict__ li,
                          float* __restrict__ li0,
                          float* __restrict__ sum,
                          unsigned* __restrict__ ticket) {
    int i = blockIdx.x * blockDim.x + threadIdx.x;
    if (i < N_NODES) li0[i] = li[(long)i * FEAT];   // pack feature column 0
    if (i == 0) { *sum = 0.0f; *ticket = 0u; }
}

// ---------------- primary path: LDS-accumulated range filter ----------------

__global__ __launch_bounds__(TB) void range_accum(
        const float* __restrict__ li0,
        const float* __restrict__ w,
        const int* __restrict__ row,
        const int* __restrict__ col,
        float* __restrict__ partial) {
    __shared__ float accl[RNODES];                  // 50 KB
    const int r  = blockIdx.x & (NRANGE - 1);       // node range
    const int s  = blockIdx.x >> 2;                 // edge slice
    const int lo = r * RNODES;

    for (int i = threadIdx.x; i < RNODES; i += TB) accl[i] = 0.0f;
    __syncthreads();

    const float4* wq = (const float4*)w   + (size_t)s * SLICE_Q;
    const int4*   rq = (const int4*)row   + (size_t)s * SLICE_Q;
    const int4*   cq = (const int4*)col   + (size_t)s * SLICE_Q;

    for (int q = threadIdx.x; q < SLICE_Q; q += TB) {
        float4 wv = wq[q];
        int4   rv = rq[q];
        int4   cv = cq[q];
        int a;
        a = rv.x - lo; if ((unsigned)a < RNODES) atomicAdd(&accl[a], wv.x * li0[cv.x]);
        a = rv.y - lo; if ((unsigned)a < RNODES) atomicAdd(&accl[a], wv.y * li0[cv.y]);
        a = rv.z - lo; if ((unsigned)a < RNODES) atomicAdd(&accl[a], wv.z * li0[cv.z]);
        a = rv.w - lo; if ((unsigned)a < RNODES) atomicAdd(&accl[a], wv.w * li0[cv.w]);
    }
    __syncthreads();

    float4* pdst = (float4*)(partial + (size_t)blockIdx.x * RNODES);
    const float4* psrc = (const float4*)accl;
    for (int i = threadIdx.x; i < RNODES / 4; i += TB) pdst[i] = psrc[i];
}

__global__ void reduce_fin(const float* __restrict__ partial,
                           float* __restrict__ sum,
                           unsigned* __restrict__ ticket,
                           float* __restrict__ out) {
    int g = blockIdx.x * blockDim.x + threadIdx.x;  // float4-group of 4 nodes
    float local = 0.0f;
    if (g < N_NODES / 4) {
        int r  = g / (RNODES / 4);
        int gl = g - r * (RNODES / 4);
        const float4* base = (const float4*)(partial + (size_t)r * RBLKS * RNODES) + gl;
        float ax = 0.0f, ay = 0.0f, az = 0.0f, aw = 0.0f;
        #pragma unroll 8
        for (int b = 0; b < RBLKS; ++b) {
            float4 p = base[(size_t)b * (RNODES / 4)];
            ax += p.x; ay += p.y; az += p.z; aw += p.w;
        }
        local = fmaxf(ax, 0.0f) + fmaxf(ay, 0.0f) +
                fmaxf(az, 0.0f) + fmaxf(aw, 0.0f);
    }
    #pragma unroll
    for (int off = 32; off > 0; off >>= 1)
        local += __shfl_down(local, off, 64);
    __shared__ float sm[4];
    int wid = threadIdx.x >> 6;
    if ((threadIdx.x & 63) == 0) sm[wid] = local;
    __syncthreads();
    if (threadIdx.x == 0) {
        atomicAdd(sum, sm[0] + sm[1] + sm[2] + sm[3]);
        __threadfence();
        unsigned old = atomicAdd(ticket, 1u);
        if (old == gridDim.x - 1) {
            __threadfence();
            float v = *(volatile float*)sum;
            out[0] = 1.0f / (1.0f + expf(-v));
        }
    }
}

// ---------------- fallback path (ws too small): global atomics ----------------

__global__ void zero_acc(float* __restrict__ acc) {
    int i = blockIdx.x * blockDim.x + threadIdx.x;
    if (i < N_NODES) acc[i] = 0.0f;
}

__global__ void edge_scatter4(const float* __restrict__ li0,
                              const float* __restrict__ w,
                              const int* __restrict__ row,
                              const int* __restrict__ col,
                              float* __restrict__ acc) {
    int t = blockIdx.x * blockDim.x + threadIdx.x;
    if (t < N_EDGES / 4) {
        float4 wv = ((const float4*)w)[t];
        int4   rv = ((const int4*)row)[t];
        int4   cv = ((const int4*)col)[t];
        atomicAdd(&acc[rv.x], wv.x * li0[cv.x]);
        atomicAdd(&acc[rv.y], wv.y * li0[cv.y]);
        atomicAdd(&acc[rv.z], wv.z * li0[cv.z]);
        atomicAdd(&acc[rv.w], wv.w * li0[cv.w]);
    }
}

__global__ void relu_sum_fin(const float* __restrict__ acc,
                             float* __restrict__ sum,
                             unsigned* __restrict__ ticket,
                             float* __restrict__ out) {
    float local = 0.0f;
    for (int i = blockIdx.x * blockDim.x + threadIdx.x; i < N_NODES / 4;
         i += gridDim.x * blockDim.x) {
        float4 a = ((const float4*)acc)[i];
        local += fmaxf(a.x, 0.0f) + fmaxf(a.y, 0.0f) +
                 fmaxf(a.z, 0.0f) + fmaxf(a.w, 0.0f);
    }
    #pragma unroll
    for (int off = 32; off > 0; off >>= 1)
        local += __shfl_down(local, off, 64);
    __shared__ float sm[4];
    int wid = threadIdx.x >> 6;
    if ((threadIdx.x & 63) == 0) sm[wid] = local;
    __syncthreads();
    if (threadIdx.x == 0) {
        atomicAdd(sum, sm[0] + sm[1] + sm[2] + sm[3]);
        __threadfence();
        unsigned old = atomicAdd(ticket, 1u);
        if (old == gridDim.x - 1) {
            __threadfence();
            float v = *(volatile float*)sum;
            out[0] = 1.0f / (1.0f + expf(-v));
        }
    }
}

extern "C" void kernel_launch(void* const* d_in, const int* in_sizes, int n_in,
                              void* d_out, int out_size, void* d_ws, size_t ws_size,
                              hipStream_t stream) {
    const float* li  = (const float*)d_in[0];
    const float* w   = (const float*)d_in[1];
    const int*   row = (const int*)d_in[2];
    const int*   col = (const int*)d_in[3];
    float* out = (float*)d_out;

    size_t need = (size_t)N_NODES * 4
                + (size_t)NRANGE * RBLKS * RNODES * 4
                + 16;

    if (ws_size >= need) {
        float*    li0     = (float*)d_ws;
        float*    partial = li0 + N_NODES;
        float*    sum     = partial + (size_t)NRANGE * RBLKS * RNODES;
        unsigned* ticket  = (unsigned*)(sum + 1);

        pack_zero<<<(N_NODES + 255) / 256, 256, 0, stream>>>(li, li0, sum, ticket);
        range_accum<<<NRANGE * RBLKS, TB, 0, stream>>>(li0, w, row, col, partial);
        reduce_fin<<<(N_NODES / 4 + 255) / 256, 256, 0, stream>>>(partial, sum, ticket, out);
    } else {
        float*    acc    = (float*)d_ws;
        float*    li0    = acc + N_NODES;
        float*    sum    = li0 + N_NODES;
        unsigned* ticket = (unsigned*)(sum + 1);

        pack_zero<<<(N_NODES + 255) / 256, 256, 0, stream>>>(li, li0, sum, ticket);
        zero_acc<<<(N_NODES + 255) / 256, 256, 0, stream>>>(acc);
        edge_scatter4<<<(N_EDGES / 4 + 255) / 256, 256, 0, stream>>>(li0, w, row, col, acc);
        relu_sum_fin<<<49, 256, 0, stream>>>(acc, sum, ticket, out);
    }
}